// Round 1
// baseline (287.816 us; speedup 1.0000x reference)
//
#include <hip/hip_runtime.h>
#include <stdint.h>

#define KCAND 9
#define BATCH 16
#define NPRED 30000
#define NGT   64

__global__ __launch_bounds__(256) void atss_kernel(
    const float* __restrict__ pred,   // [B, N, 4] cxcywh
    const float* __restrict__ gt,     // [B, G, 4] cxcywh
    float* __restrict__ out)          // [4][B*G*K] float32
{
#pragma clang fp contract(off)
    const int wave = threadIdx.x >> 6;
    const int lane = threadIdx.x & 63;
    const int w = blockIdx.x * 4 + wave;      // global wave id = b*G + g
    const int b = w >> 6;
    const int g = w & 63;

    // ---- GT box ----
    const float4 gtb = ((const float4*)gt)[b * NGT + g];
    const float gcx = gtb.x, gcy = gtb.y;

    // ---- per-lane top-9 scan over strided candidates ----
    unsigned long long top[KCAND];
#pragma unroll
    for (int i = 0; i < KCAND; ++i) top[i] = ~0ULL;

    const float4* predb = (const float4*)pred + (size_t)b * NPRED;
    for (int i = lane; i < NPRED; i += 64) {
        float4 p = predb[i];
        float dx = __fsub_rn(gcx, p.x);
        float dy = __fsub_rn(gcy, p.y);
        float d2 = __fadd_rn(__fmul_rn(dx, dx), __fmul_rn(dy, dy));
        float dist = sqrtf(d2);   // IEEE sqrt (no fast-math): matches np, monotone
        // key: (dist bits, idx) — nonneg f32 bits order == float order;
        // tie on dist -> lower idx wins, matching jax.lax.top_k stability.
        unsigned long long key =
            ((unsigned long long)__float_as_uint(dist) << 32) | (unsigned)i;
        if (key < top[KCAND - 1]) {
            // insertion via unrolled swap chain (static indices -> stays in VGPRs)
#pragma unroll
            for (int j = 0; j < KCAND; ++j) {
                unsigned long long t = top[j];
                bool sw = key < t;
                unsigned long long lo = sw ? key : t;
                unsigned long long hi = sw ? t : key;
                top[j] = lo;
                key = hi;
            }
        }
    }

    // ---- wave-wide merge: 9 rounds of u64-min over each lane's head ----
    unsigned long long myKey = 0;  // lane k (k<9) ends holding k-th smallest
#pragma unroll
    for (int k = 0; k < KCAND; ++k) {
        unsigned long long h = top[0];
        unsigned long long m = h;
#pragma unroll
        for (int s = 1; s < 64; s <<= 1) {
            unsigned long long o = __shfl_xor(m, s, 64);
            m = o < m ? o : m;
        }
        if (lane == k) myKey = m;
        if (h == m) {
            // pop head (keys are unique: idx field distinct per lane set)
#pragma unroll
            for (int j = 0; j < KCAND - 1; ++j) top[j] = top[j + 1];
            top[KCAND - 1] = ~0ULL;
        }
    }

    // ---- lanes 0..8: IoU + adaptive threshold + outputs ----
    const bool active = (lane < KCAND);
    const unsigned idx = active ? (unsigned)(myKey & 0xffffffffu) : 0u;

    float4 pb = predb[idx];   // safe: idx==0 for inactive lanes

    // gt xyxy
    float gx1 = gcx - 0.5f * gtb.z, gy1 = gcy - 0.5f * gtb.w;
    float gx2 = gcx + 0.5f * gtb.z, gy2 = gcy + 0.5f * gtb.w;
    // candidate xyxy
    float kx1 = pb.x - 0.5f * pb.z, ky1 = pb.y - 0.5f * pb.w;
    float kx2 = pb.x + 0.5f * pb.z, ky2 = pb.y + 0.5f * pb.w;

    float ltx = fmaxf(gx1, kx1), lty = fmaxf(gy1, ky1);
    float rbx = fminf(gx2, kx2), rby = fminf(gy2, ky2);
    float wv = fmaxf(rbx - ltx, 0.0f);
    float hv = fmaxf(rby - lty, 0.0f);
    float inter  = wv * hv;
    float area_a = (gx2 - gx1) * (gy2 - gy1);
    float area_b = (kx2 - kx1) * (ky2 - ky1);
    float iou = inter / ((area_a + area_b) - inter);

    // mean over 9 (lanes >= 9 contribute 0)
    float v = active ? iou : 0.0f;
    float s = v;
#pragma unroll
    for (int m = 1; m < 64; m <<= 1) s += __shfl_xor(s, m, 64);
    float mean = s / 9.0f;

    float dev = active ? (iou - mean) : 0.0f;
    float ss = dev * dev;
#pragma unroll
    for (int m = 1; m < 64; m <<= 1) ss += __shfl_xor(ss, m, 64);
    float stdv = sqrtf(ss / 8.0f);       // ddof = 1
    float thr = mean + stdv;

    bool inside = (gx1 <= pb.x) && (pb.x <= gx2) &&
                  (gy1 <= pb.y) && (pb.y <= gy2);
    bool maskk = (iou >= thr) && inside;

    if (active) {
        const size_t chunk = (size_t)BATCH * NGT * KCAND;   // 9216
        const size_t o = (size_t)w * KCAND + lane;
        out[0 * chunk + o] = maskk ? (float)idx : -1.0f;    // pred_idx
        out[1 * chunk + o] = maskk ? (float)g   : -1.0f;    // gt_idx
        out[2 * chunk + o] = maskk ? 1.0f : 0.0f;           // mask
        out[3 * chunk + o] = iou;                           // ious
    }
}

extern "C" void kernel_launch(void* const* d_in, const int* in_sizes, int n_in,
                              void* d_out, int out_size, void* d_ws, size_t ws_size,
                              hipStream_t stream) {
    const float* pred = (const float*)d_in[0];   // [16, 30000, 4] f32
    const float* gtb  = (const float*)d_in[1];   // [16, 64, 4] f32
    float* out = (float*)d_out;                  // 4 * 16*64*9 = 36864 f32

    // 1024 waves (one per (b,g)), 4 waves per 256-thread block -> 256 blocks
    atss_kernel<<<(BATCH * NGT) / 4, 256, 0, stream>>>(pred, gtb, out);
}

// Round 2
// 141.842 us; speedup vs baseline: 2.0291x; 2.0291x over previous
//
#include <hip/hip_runtime.h>
#include <stdint.h>

typedef unsigned long long u64;

#define KCAND 9
#define BATCH 16
#define NPRED 30000
#define NGT   64
#define TPB   256   // one block per (b,g) row

__device__ __forceinline__ u64 wave_min_u64(u64 v) {
#pragma unroll
    for (int s = 1; s < 64; s <<= 1) {
        u64 o = __shfl_xor(v, s, 64);
        v = o < v ? o : v;
    }
    return v;
}

__global__ __launch_bounds__(TPB, 4) void atss_kernel(
    const float* __restrict__ pred,   // [B, N, 4] cxcywh
    const float* __restrict__ gt,     // [B, G, 4] cxcywh
    float* __restrict__ out)          // [4][B*G*K] float32
{
#pragma clang fp contract(off)
    const int tid  = threadIdx.x;
    const int lane = tid & 63;
    const int wv   = tid >> 6;        // wave id in block, 0..3
    const int w    = blockIdx.x;      // row id = b*NGT + g
    const int b    = w >> 6;
    const int g    = w & 63;

    const float4 gtb = ((const float4*)gt)[w];
    const float gcx = gtb.x, gcy = gtb.y;
    const float4* predb = (const float4*)pred + (size_t)b * NPRED;

    // ---- per-thread sorted top-9 in explicit registers (no array -> no scratch) ----
    u64 t0=~0ULL,t1=~0ULL,t2=~0ULL,t3=~0ULL,t4=~0ULL,t5=~0ULL,t6=~0ULL,t7=~0ULL,t8=~0ULL;

#define SWAPSTEP(T) { bool c_ = x < (T); u64 lo_ = c_ ? x : (T); u64 hi_ = c_ ? (T) : x; (T) = lo_; x = hi_; }
#define INSERT(KEY) { u64 k_ = (KEY); if (k_ < t8) { u64 x = k_; \
    SWAPSTEP(t0) SWAPSTEP(t1) SWAPSTEP(t2) SWAPSTEP(t3) SWAPSTEP(t4) \
    SWAPSTEP(t5) SWAPSTEP(t6) SWAPSTEP(t7) SWAPSTEP(t8) } }

    // key: (dist f32 bits << 32) | idx -- nonneg float bit order == value order,
    // tie on dist -> lower idx wins (matches jax.lax.top_k stability).
    for (int i = tid; i < NPRED; i += TPB * 4) {
        const int i1 = i + TPB, i2 = i + 2 * TPB, i3 = i + 3 * TPB;
        const bool v1 = i1 < NPRED, v2 = i2 < NPRED, v3 = i3 < NPRED;
        float4 p0 = predb[i];
        float4 p1 = predb[v1 ? i1 : i];
        float4 p2 = predb[v2 ? i2 : i];
        float4 p3 = predb[v3 ? i3 : i];

        float dx0 = __fsub_rn(gcx, p0.x), dy0 = __fsub_rn(gcy, p0.y);
        float dx1 = __fsub_rn(gcx, p1.x), dy1 = __fsub_rn(gcy, p1.y);
        float dx2 = __fsub_rn(gcx, p2.x), dy2 = __fsub_rn(gcy, p2.y);
        float dx3 = __fsub_rn(gcx, p3.x), dy3 = __fsub_rn(gcy, p3.y);
        float d0 = sqrtf(__fadd_rn(__fmul_rn(dx0,dx0), __fmul_rn(dy0,dy0)));
        float d1 = sqrtf(__fadd_rn(__fmul_rn(dx1,dx1), __fmul_rn(dy1,dy1)));
        float d2 = sqrtf(__fadd_rn(__fmul_rn(dx2,dx2), __fmul_rn(dy2,dy2)));
        float d3 = sqrtf(__fadd_rn(__fmul_rn(dx3,dx3), __fmul_rn(dy3,dy3)));

        u64 k0 = ((u64)__float_as_uint(d0) << 32) | (unsigned)i;
        u64 k1 = v1 ? (((u64)__float_as_uint(d1) << 32) | (unsigned)i1) : ~0ULL;
        u64 k2 = v2 ? (((u64)__float_as_uint(d2) << 32) | (unsigned)i2) : ~0ULL;
        u64 k3 = v3 ? (((u64)__float_as_uint(d3) << 32) | (unsigned)i3) : ~0ULL;

        INSERT(k0) INSERT(k1) INSERT(k2) INSERT(k3)
    }

    // ---- wave-local merge: 9 rounds of u64-min pop; lanes 0..8 get wave top-9 ----
    u64 my = 0;
#pragma unroll
    for (int k = 0; k < KCAND; ++k) {
        u64 h = t0;
        u64 m = wave_min_u64(h);
        if (lane == k) my = m;
        if (h == m) {   // keys unique (distinct idx) -> exactly one popper
            t0=t1; t1=t2; t2=t3; t3=t4; t4=t5; t5=t6; t6=t7; t7=t8; t8=~0ULL;
        }
    }

    // ---- cross-wave merge through LDS ----
    __shared__ u64 smem[4 * KCAND];
    if (lane < KCAND) smem[wv * KCAND + lane] = my;
    __syncthreads();

    if (wv != 0) return;

    u64 key = (lane < 4 * KCAND) ? smem[lane] : ~0ULL;
    u64 fin = 0;
#pragma unroll
    for (int k = 0; k < KCAND; ++k) {
        u64 m = wave_min_u64(key);
        if (lane == k) fin = m;
        if (key == m) key = ~0ULL;
    }

    // ---- lanes 0..8: IoU + adaptive threshold + outputs ----
    const bool active = (lane < KCAND);
    const unsigned idx = active ? (unsigned)(fin & 0xffffffffu) : 0u;

    float4 pb = predb[idx];

    float gx1 = gcx - 0.5f * gtb.z, gy1 = gcy - 0.5f * gtb.w;
    float gx2 = gcx + 0.5f * gtb.z, gy2 = gcy + 0.5f * gtb.w;
    float kx1 = pb.x - 0.5f * pb.z, ky1 = pb.y - 0.5f * pb.w;
    float kx2 = pb.x + 0.5f * pb.z, ky2 = pb.y + 0.5f * pb.w;

    float ltx = fmaxf(gx1, kx1), lty = fmaxf(gy1, ky1);
    float rbx = fminf(gx2, kx2), rby = fminf(gy2, ky2);
    float wvd = fmaxf(rbx - ltx, 0.0f);
    float hvd = fmaxf(rby - lty, 0.0f);
    float inter  = wvd * hvd;
    float area_a = (gx2 - gx1) * (gy2 - gy1);
    float area_b = (kx2 - kx1) * (ky2 - ky1);
    float iou = inter / ((area_a + area_b) - inter);

    float v = active ? iou : 0.0f;
    float s = v;
#pragma unroll
    for (int m = 1; m < 64; m <<= 1) s += __shfl_xor(s, m, 64);
    float mean = s / 9.0f;

    float dev = active ? (iou - mean) : 0.0f;
    float ss = dev * dev;
#pragma unroll
    for (int m = 1; m < 64; m <<= 1) ss += __shfl_xor(ss, m, 64);
    float stdv = sqrtf(ss / 8.0f);    // ddof = 1
    float thr = mean + stdv;

    bool inside = (gx1 <= pb.x) && (pb.x <= gx2) &&
                  (gy1 <= pb.y) && (pb.y <= gy2);
    bool maskk = (iou >= thr) && inside;

    if (active) {
        const size_t chunk = (size_t)BATCH * NGT * KCAND;   // 9216
        const size_t o = (size_t)w * KCAND + lane;
        out[0 * chunk + o] = maskk ? (float)idx : -1.0f;    // pred_idx
        out[1 * chunk + o] = maskk ? (float)g   : -1.0f;    // gt_idx
        out[2 * chunk + o] = maskk ? 1.0f : 0.0f;           // mask
        out[3 * chunk + o] = iou;                           // ious
    }
#undef INSERT
#undef SWAPSTEP
}

extern "C" void kernel_launch(void* const* d_in, const int* in_sizes, int n_in,
                              void* d_out, int out_size, void* d_ws, size_t ws_size,
                              hipStream_t stream) {
    const float* pred = (const float*)d_in[0];   // [16, 30000, 4] f32
    const float* gtb  = (const float*)d_in[1];   // [16, 64, 4] f32
    float* out = (float*)d_out;                  // 4 * 16*64*9 = 36864 f32

    // one 256-thread block per (b,g) row: 1024 blocks, 4 blocks/CU
    atss_kernel<<<BATCH * NGT, TPB, 0, stream>>>(pred, gtb, out);
}

// Round 3
// 98.200 us; speedup vs baseline: 2.9309x; 1.4444x over previous
//
#include <hip/hip_runtime.h>
#include <stdint.h>

typedef unsigned long long u64;

#define KCAND 9
#define BATCH 16
#define NPRED 30000
#define NGT   64
#define TPB   256
// "empty slot" key: (+inf dist bits, idx=~0) -> any real key compares smaller
#define INITKEY 0x7F800000FFFFFFFFULL

__device__ __forceinline__ u64 wave_min_u64(u64 v) {
#pragma unroll
    for (int s = 1; s < 64; s <<= 1) {
        u64 o = __shfl_xor(v, s, 64);
        v = o < v ? o : v;
    }
    return v;
}

__global__ __launch_bounds__(TPB, 4) void atss_kernel(
    const float* __restrict__ pred,   // [B, N, 4] cxcywh
    const float* __restrict__ gt,     // [B, G, 4] cxcywh
    float* __restrict__ out)          // [4][B*G*K] float32
{
#pragma clang fp contract(off)
    const int tid  = threadIdx.x;
    const int lane = tid & 63;
    const int wvid = tid >> 6;        // wave in block, 0..3
    const int w    = blockIdx.x;      // row id = b*NGT + g
    const int b    = w >> 6;
    const int g    = w & 63;

    const float4 gtb = ((const float4*)gt)[w];
    const float gcx = gtb.x, gcy = gtb.y;
    const float2* p2    = (const float2*)(pred + (size_t)b * NPRED * 4); // xy at p2[2*i]
    const float4* pred4 = (const float4*)pred + (size_t)b * NPRED;

    // wave-shared top-9: sorted ascending in lanes 0..8 (u64 key = d2bits<<32 | idx)
    u64 val = INITKEY;
    float Tf = __uint_as_float(0x7F800000u);   // +inf until 9 entries present

    // each wave handles i = t*1024 + wvid*256 + j*64 + lane
    for (int t = 0; t < 30; ++t) {
        const int i0 = t * 1024 + wvid * 256 + lane;
        float d2[4]; int ii[4];
#pragma unroll
        for (int j = 0; j < 4; ++j) {
            const int i = i0 + j * 64;
            ii[j] = i;
            const bool v = i < NPRED;
            const int ic = v ? i : 0;
            float2 xy = p2[2 * ic];
            float dx = __fsub_rn(gcx, xy.x);
            float dy = __fsub_rn(gcy, xy.y);
            float d = __fadd_rn(__fmul_rn(dx, dx), __fmul_rn(dy, dy));
            d2[j] = v ? d : __uint_as_float(0x7F800000u);   // +inf for tail
        }
        float dmin = fminf(fminf(d2[0], d2[1]), fminf(d2[2], d2[3]));
        // fast reject: non-strict so dist-ties at the boundary reach the exact path
        if (__ballot(dmin <= Tf) == 0ULL) continue;

#pragma unroll
        for (int j = 0; j < 4; ++j) {
            u64 pend = __ballot(d2[j] <= Tf);
            while (pend) {
                const int src = __ffsll(pend) - 1;
                pend &= pend - 1;
                const unsigned kd = __shfl(__float_as_uint(d2[j]), src, 64);
                const unsigned ki = (unsigned)__shfl(ii[j], src, 64);
                const u64 key = ((u64)kd << 32) | ki;
                u64 Tkey = __shfl(val, 8, 64);
                if (key < Tkey) {                 // wave-uniform
                    const u64 ltm = __ballot(val < key) & 0x1FFULL;
                    const int pos = __popcll(ltm);
                    const u64 sh = __shfl_up(val, 1, 64);
                    if (lane < KCAND) {
                        if (lane == pos)      val = key;
                        else if (lane > pos)  val = sh;
                    }
                    Tkey = __shfl(val, 8, 64);
                    Tf = __uint_as_float((unsigned)(Tkey >> 32));
                    pend &= __ballot(d2[j] <= Tf);   // re-prune with tighter T
                }
            }
        }
    }

    // ---- cross-wave merge through LDS (keys exact: (d2,idx) lex) ----
    __shared__ u64 smem[4 * KCAND];
    if (lane < KCAND) smem[wvid * KCAND + lane] = val;
    __syncthreads();

    if (wvid != 0) return;

    u64 key = (lane < 4 * KCAND) ? smem[lane] : ~0ULL;
    u64 fin = 0;
#pragma unroll
    for (int k = 0; k < KCAND; ++k) {
        u64 m = wave_min_u64(key);
        if (lane == k) fin = m;
        if (key == m) key = ~0ULL;   // keys unique (distinct idx)
    }

    // ---- lanes 0..8: IoU + adaptive threshold + outputs ----
    const bool active = (lane < KCAND);
    const unsigned idx = active ? (unsigned)(fin & 0xffffffffu) : 0u;

    float4 pb = pred4[idx];

    float gx1 = gcx - 0.5f * gtb.z, gy1 = gcy - 0.5f * gtb.w;
    float gx2 = gcx + 0.5f * gtb.z, gy2 = gcy + 0.5f * gtb.w;
    float kx1 = pb.x - 0.5f * pb.z, ky1 = pb.y - 0.5f * pb.w;
    float kx2 = pb.x + 0.5f * pb.z, ky2 = pb.y + 0.5f * pb.w;

    float ltx = fmaxf(gx1, kx1), lty = fmaxf(gy1, ky1);
    float rbx = fminf(gx2, kx2), rby = fminf(gy2, ky2);
    float wvd = fmaxf(rbx - ltx, 0.0f);
    float hvd = fmaxf(rby - lty, 0.0f);
    float inter  = wvd * hvd;
    float area_a = (gx2 - gx1) * (gy2 - gy1);
    float area_b = (kx2 - kx1) * (ky2 - ky1);
    float iou = inter / ((area_a + area_b) - inter);

    float v = active ? iou : 0.0f;
    float s = v;
#pragma unroll
    for (int m = 1; m < 64; m <<= 1) s += __shfl_xor(s, m, 64);
    float mean = s / 9.0f;

    float dev = active ? (iou - mean) : 0.0f;
    float ss = dev * dev;
#pragma unroll
    for (int m = 1; m < 64; m <<= 1) ss += __shfl_xor(ss, m, 64);
    float stdv = sqrtf(ss / 8.0f);    // ddof = 1
    float thr = mean + stdv;

    bool inside = (gx1 <= pb.x) && (pb.x <= gx2) &&
                  (gy1 <= pb.y) && (pb.y <= gy2);
    bool maskk = (iou >= thr) && inside;

    if (active) {
        const size_t chunk = (size_t)BATCH * NGT * KCAND;   // 9216
        const size_t o = (size_t)w * KCAND + lane;
        out[0 * chunk + o] = maskk ? (float)idx : -1.0f;    // pred_idx
        out[1 * chunk + o] = maskk ? (float)g   : -1.0f;    // gt_idx
        out[2 * chunk + o] = maskk ? 1.0f : 0.0f;           // mask
        out[3 * chunk + o] = iou;                           // ious
    }
}

extern "C" void kernel_launch(void* const* d_in, const int* in_sizes, int n_in,
                              void* d_out, int out_size, void* d_ws, size_t ws_size,
                              hipStream_t stream) {
    const float* pred = (const float*)d_in[0];   // [16, 30000, 4] f32
    const float* gtb  = (const float*)d_in[1];   // [16, 64, 4] f32
    float* out = (float*)d_out;                  // 4 * 16*64*9 = 36864 f32

    // one 256-thread block per (b,g) row: 1024 blocks, 4 blocks/CU
    atss_kernel<<<BATCH * NGT, TPB, 0, stream>>>(pred, gtb, out);
}

// Round 4
// 97.493 us; speedup vs baseline: 2.9522x; 1.0073x over previous
//
#include <hip/hip_runtime.h>
#include <stdint.h>

typedef unsigned long long u64;

#define KCAND 9
#define BATCH 16
#define NPRED 30000
#define NGT   64
#define TPB   256
#define UNR   8
// elements per block per t-iteration: 256 threads * 8 = 2048
#define NT    15   // ceil(30000/2048)
#define INITKEY 0x7F800000FFFFFFFFULL

__device__ __forceinline__ u64 wave_min_u64(u64 v) {
#pragma unroll
    for (int s = 1; s < 64; s <<= 1) {
        u64 o = __shfl_xor(v, s, 64);
        v = o < v ? o : v;
    }
    return v;
}

// pre-pass: compact xy into [B][N] float2 (halves cache traffic, dense loads)
__global__ __launch_bounds__(256) void compact_xy(
    const float* __restrict__ pred, float2* __restrict__ xy)
{
    int e = blockIdx.x * 256 + threadIdx.x;
    if (e < BATCH * NPRED) {
        float4 p = ((const float4*)pred)[e];
        xy[e] = make_float2(p.x, p.y);
    }
}

// S2 = float2 stride per element: 1 (compact ws) or 2 (raw pred, fallback)
template <int S2>
__global__ __launch_bounds__(TPB, 4) void atss_kernel(
    const float2* __restrict__ xy,    // [B][N] xy, stride S2 float2s
    const float*  __restrict__ pred,  // [B, N, 4] cxcywh (epilogue only)
    const float*  __restrict__ gt,    // [B, G, 4] cxcywh
    float* __restrict__ out)          // [4][B*G*K] float32
{
#pragma clang fp contract(off)
    const int tid  = threadIdx.x;
    const int lane = tid & 63;
    const int wvid = tid >> 6;

    // XCD-aware swizzle: blocks round-robin XCDs by blockIdx%8, so give
    // XCD k only images {k, k+8}: per-XCD L2 working set ~0.5 MB (fits 4 MB).
    const int b = (blockIdx.x & 7) + 8 * (blockIdx.x >> 9);
    const int g = (blockIdx.x >> 3) & 63;
    const int w = b * NGT + g;        // logical row for gt/output

    const float4 gtb = ((const float4*)gt)[w];
    const float gcx = gtb.x, gcy = gtb.y;
    const float2* xyb   = xy + (size_t)b * NPRED * S2;
    const float4* pred4 = (const float4*)pred + (size_t)b * NPRED;

    // wave-shared top-9: sorted ascending in lanes 0..8 (u64 key = d2bits<<32 | idx)
    u64 val = INITKEY;
    float Tf = __uint_as_float(0x7F800000u);

    for (int t = 0; t < NT; ++t) {
        const int i0 = t * (TPB * UNR) + wvid * (64 * UNR) + lane;
        float d2[UNR];
#pragma unroll
        for (int j = 0; j < UNR; ++j) {
            const int i = i0 + j * 64;
            const bool v = i < NPRED;
            float2 p = xyb[(v ? i : 0) * S2];
            float dx = __fsub_rn(gcx, p.x);
            float dy = __fsub_rn(gcy, p.y);
            float d = __fadd_rn(__fmul_rn(dx, dx), __fmul_rn(dy, dy));
            d2[j] = v ? d : __uint_as_float(0x7F800000u);
        }
        float dmin = d2[0];
#pragma unroll
        for (int j = 1; j < UNR; ++j) dmin = fminf(dmin, d2[j]);
        if (__ballot(dmin <= Tf) == 0ULL) continue;   // fast reject (non-strict)

#pragma unroll
        for (int j = 0; j < UNR; ++j) {
            u64 pend = __ballot(d2[j] <= Tf);
            while (pend) {
                const int src = __ffsll(pend) - 1;
                pend &= pend - 1;
                const unsigned kd = __shfl(__float_as_uint(d2[j]), src, 64);
                const unsigned ki = (unsigned)(i0 + j * 64 - lane + src);
                const u64 key = ((u64)kd << 32) | ki;
                u64 Tkey = __shfl(val, 8, 64);
                if (key < Tkey) {                 // wave-uniform
                    const u64 ltm = __ballot(val < key) & 0x1FFULL;
                    const int pos = __popcll(ltm);
                    const u64 sh = __shfl_up(val, 1, 64);
                    if (lane < KCAND) {
                        if (lane == pos)      val = key;
                        else if (lane > pos)  val = sh;
                    }
                    Tkey = __shfl(val, 8, 64);
                    Tf = __uint_as_float((unsigned)(Tkey >> 32));
                    pend &= __ballot(d2[j] <= Tf);   // re-prune
                }
            }
        }
    }

    // ---- cross-wave merge through LDS ----
    __shared__ u64 smem[4 * KCAND];
    if (lane < KCAND) smem[wvid * KCAND + lane] = val;
    __syncthreads();

    if (wvid != 0) return;

    u64 key = (lane < 4 * KCAND) ? smem[lane] : ~0ULL;
    u64 fin = 0;
#pragma unroll
    for (int k = 0; k < KCAND; ++k) {
        u64 m = wave_min_u64(key);
        if (lane == k) fin = m;
        if (key == m) key = ~0ULL;   // keys unique (distinct idx)
    }

    // ---- lanes 0..8: IoU + adaptive threshold + outputs ----
    const bool active = (lane < KCAND);
    const unsigned idx = active ? (unsigned)(fin & 0xffffffffu) : 0u;

    float4 pb = pred4[idx];

    float gx1 = gcx - 0.5f * gtb.z, gy1 = gcy - 0.5f * gtb.w;
    float gx2 = gcx + 0.5f * gtb.z, gy2 = gcy + 0.5f * gtb.w;
    float kx1 = pb.x - 0.5f * pb.z, ky1 = pb.y - 0.5f * pb.w;
    float kx2 = pb.x + 0.5f * pb.z, ky2 = pb.y + 0.5f * pb.w;

    float ltx = fmaxf(gx1, kx1), lty = fmaxf(gy1, ky1);
    float rbx = fminf(gx2, kx2), rby = fminf(gy2, ky2);
    float wvd = fmaxf(rbx - ltx, 0.0f);
    float hvd = fmaxf(rby - lty, 0.0f);
    float inter  = wvd * hvd;
    float area_a = (gx2 - gx1) * (gy2 - gy1);
    float area_b = (kx2 - kx1) * (ky2 - ky1);
    float iou = inter / ((area_a + area_b) - inter);

    float v = active ? iou : 0.0f;
    float s = v;
#pragma unroll
    for (int m = 1; m < 64; m <<= 1) s += __shfl_xor(s, m, 64);
    float mean = s / 9.0f;

    float dev = active ? (iou - mean) : 0.0f;
    float ss = dev * dev;
#pragma unroll
    for (int m = 1; m < 64; m <<= 1) ss += __shfl_xor(ss, m, 64);
    float stdv = sqrtf(ss / 8.0f);    // ddof = 1
    float thr = mean + stdv;

    bool inside = (gx1 <= pb.x) && (pb.x <= gx2) &&
                  (gy1 <= pb.y) && (pb.y <= gy2);
    bool maskk = (iou >= thr) && inside;

    if (active) {
        const size_t chunk = (size_t)BATCH * NGT * KCAND;   // 9216
        const size_t o = (size_t)w * KCAND + lane;
        out[0 * chunk + o] = maskk ? (float)idx : -1.0f;    // pred_idx
        out[1 * chunk + o] = maskk ? (float)g   : -1.0f;    // gt_idx
        out[2 * chunk + o] = maskk ? 1.0f : 0.0f;           // mask
        out[3 * chunk + o] = iou;                           // ious
    }
}

extern "C" void kernel_launch(void* const* d_in, const int* in_sizes, int n_in,
                              void* d_out, int out_size, void* d_ws, size_t ws_size,
                              hipStream_t stream) {
    const float* pred = (const float*)d_in[0];   // [16, 30000, 4] f32
    const float* gtb  = (const float*)d_in[1];   // [16, 64, 4] f32
    float* out = (float*)d_out;                  // 4 * 16*64*9 = 36864 f32

    const size_t need = (size_t)BATCH * NPRED * sizeof(float2);   // 3.84 MB
    if (ws_size >= need) {
        float2* xy = (float2*)d_ws;
        compact_xy<<<(BATCH * NPRED + 255) / 256, 256, 0, stream>>>(pred, xy);
        atss_kernel<1><<<BATCH * NGT, TPB, 0, stream>>>(xy, pred, gtb, out);
    } else {
        atss_kernel<2><<<BATCH * NGT, TPB, 0, stream>>>(
            (const float2*)pred, pred, gtb, out);
    }
}